// Round 7
// baseline (698.643 us; speedup 1.0000x reference)
//
#include <hip/hip_runtime.h>
#include <hip/hip_bf16.h>
#include <math.h>

typedef __hip_bfloat16 bf16;
typedef __bf16 bf16x8 __attribute__((ext_vector_type(8)));
typedef float f32x4 __attribute__((ext_vector_type(4)));

#define B_ 8
#define T_ 2048
#define D_ 512
#define H_ 2048

__device__ __forceinline__ float b2f(unsigned short u) {
    return __uint_as_float((unsigned)u << 16);
}
__device__ __forceinline__ float ldf(const float* p, long i) { return p[i]; }
__device__ __forceinline__ float ldf(const bf16* p, long i) {
    return b2f(((const unsigned short*)p)[i]);
}

#define GLD16(g, l)                                                          \
    __builtin_amdgcn_global_load_lds(                                        \
        (const __attribute__((address_space(1))) void*)(g),                  \
        (__attribute__((address_space(3))) void*)(l), 16, 0, 0)

// ---------------- LayerNorm over D=512, one block (256 thr) per row ----------------
template <typename Tin>
__global__ __launch_bounds__(256) void ln_kernel(const Tin* __restrict__ x,
                                                 const float* __restrict__ g,
                                                 const float* __restrict__ bb,
                                                 bf16* __restrict__ y) {
    long base = (long)blockIdx.x * D_;
    int tid = threadIdx.x;
    float v0 = ldf(x, base + tid);
    float v1 = ldf(x, base + tid + 256);
    float s = v0 + v1;
#pragma unroll
    for (int off = 32; off > 0; off >>= 1) s += __shfl_down(s, off);
    __shared__ float red[4];
    int lane = tid & 63, wid = tid >> 6;
    if (lane == 0) red[wid] = s;
    __syncthreads();
    float mean = (red[0] + red[1] + red[2] + red[3]) * (1.0f / 512.0f);
    __syncthreads();
    float d0 = v0 - mean, d1 = v1 - mean;
    float vs = d0 * d0 + d1 * d1;
#pragma unroll
    for (int off = 32; off > 0; off >>= 1) vs += __shfl_down(vs, off);
    if (lane == 0) red[wid] = vs;
    __syncthreads();
    float var = (red[0] + red[1] + red[2] + red[3]) * (1.0f / 512.0f);
    float rstd = rsqrtf(var + 1e-5f);
    y[base + tid]       = __float2bfloat16(d0 * rstd * g[tid]       + bb[tid]);
    y[base + tid + 256] = __float2bfloat16(d1 * rstd * g[tid + 256] + bb[tid + 256]);
}

// ---------------- exp(w - rowmax(w)) : one block per row of [T,T] ----------------
__global__ __launch_bounds__(256) void expw_kernel(const float* __restrict__ w,
                                                   bf16* __restrict__ ew) {
    long base = (long)blockIdx.x * T_;
    int tid = threadIdx.x;
    float v[8];
    float mx = -3.4e38f;
#pragma unroll
    for (int i = 0; i < 8; ++i) {
        v[i] = w[base + tid + i * 256];
        mx = fmaxf(mx, v[i]);
    }
#pragma unroll
    for (int off = 32; off > 0; off >>= 1) mx = fmaxf(mx, __shfl_down(mx, off));
    __shared__ float red[4];
    if ((tid & 63) == 0) red[tid >> 6] = mx;
    __syncthreads();
    float rmax = fmaxf(fmaxf(red[0], red[1]), fmaxf(red[2], red[3]));
#pragma unroll
    for (int i = 0; i < 8; ++i)
        ew[base + tid + i * 256] = __float2bfloat16(expf(v[i] - rmax));
}

// ------- fused batch-max + kv2T build: grid (T/64, D/64), loops b internally -------
// kv2T[b][n][t]: n<512 -> expK*V (d=n); n>=512 -> expK (d=n-512)
__global__ __launch_bounds__(256) void maxkv2t_kernel(const bf16* __restrict__ K_,
                                                      const bf16* __restrict__ V_,
                                                      bf16* __restrict__ kv2t) {
    __shared__ float sev[64][65];
    __shared__ float se[64][65];
    int tx = threadIdx.x & 63, ty = threadIdx.x >> 6;
    int t0 = blockIdx.x * 64, d0 = blockIdx.y * 64;
    float mx[16];
#pragma unroll
    for (int r = 0; r < 16; ++r) mx[r] = -3.4e38f;
    for (int b = 0; b < B_; ++b) {
        long ibase = (long)b << 20;
#pragma unroll
        for (int r = 0; r < 16; ++r) {
            int tl = r * 4 + ty;
            mx[r] = fmaxf(mx[r], ldf(K_, ibase + (long)(t0 + tl) * D_ + d0 + tx));
        }
    }
    for (int b = 0; b < B_; ++b) {
        long ibase = (long)b << 20;
#pragma unroll
        for (int r = 0; r < 16; ++r) {
            int tl = r * 4 + ty;
            long mi = ibase + (long)(t0 + tl) * D_ + d0 + tx;
            float e = expf(ldf(K_, mi) - mx[r]);
            sev[tl][tx] = e * ldf(V_, mi);
            se[tl][tx] = e;
        }
        __syncthreads();
        long obase = (long)b << 21;
#pragma unroll
        for (int r = 0; r < 16; ++r) {
            int dl = r * 4 + ty;
            kv2t[obase + (long)(d0 + dl) * T_ + t0 + tx]       = __float2bfloat16(sev[tx][dl]);
            kv2t[obase + (long)(512 + d0 + dl) * T_ + t0 + tx] = __float2bfloat16(se[tx][dl]);
        }
        __syncthreads();
    }
}

// ---------------- batched weight transpose + f32->bf16: W[K,N] -> WT[N,K] ----------
struct WT6 {
    const float* src[6];
    bf16* dst[6];
    int K[6], N[6];
};
__global__ __launch_bounds__(256) void wtrans6_kernel(WT6 p) {
    int z = blockIdx.z;
    int K = p.K[z], N = p.N[z];
    int n0 = blockIdx.x * 64, k0 = blockIdx.y * 64;
    if (n0 >= N || k0 >= K) return;
    const float* W = p.src[z];
    bf16* WT = p.dst[z];
    __shared__ float s[64][65];
    int tx = threadIdx.x & 63, ty = threadIdx.x >> 6;
#pragma unroll
    for (int r = 0; r < 16; ++r) {
        int kl = r * 4 + ty;
        s[kl][tx] = W[(long)(k0 + kl) * N + n0 + tx];
    }
    __syncthreads();
#pragma unroll
    for (int r = 0; r < 16; ++r) {
        int nl = r * 4 + ty;
        WT[(long)(n0 + nl) * K + k0 + tx] = __float2bfloat16(s[tx][nl]);
    }
}

// ---------------- MFMA GEMM: C = epi(A@Bt^T + bias) [+res] ------------------------
// BM x 128 macro-tile, 4 waves. planeStride!=0: N split into 512-col planes;
// per-plane bias b0/b1/b2 and mode = (modes>>(2*plane))&3. mode 0=none 1=sigmoid 2=gelu.
template <int BM>
__global__ __launch_bounds__(256, 2) void mfma_gemm(
    const bf16* __restrict__ A, const bf16* __restrict__ Bt,
    const float* __restrict__ b0, const float* __restrict__ b1,
    const float* __restrict__ b2,
    bf16* __restrict__ Cb, float* __restrict__ Cf,
    const bf16* __restrict__ resb, const float* __restrict__ resf,
    int M, int N, int K, int modes, long bsB, long bsC, long planeStride) {
    constexpr int MI = BM / 32;
    constexpr int NA = BM / 64;
    __shared__ short As[BM * 32];
    __shared__ short Bs[128 * 32];
    int tid = threadIdx.x;
    int lane = tid & 63, wave = tid >> 6;
    int wm = wave & 1, wn = wave >> 1;
    int m0 = blockIdx.y * BM, n0 = blockIdx.x * 128;
    const short* Ag = (const short*)A;
    const short* Bg = (const short*)Bt + (long)blockIdx.z * bsB;

    int lr = lane >> 2;
    int le = (lane & 3) * 8;
    const short* ga[NA];
    short* la[NA];
#pragma unroll
    for (int i = 0; i < NA; ++i) {
        ga[i] = Ag + (long)(m0 + wave * (BM / 4) + i * 16 + lr) * K + le;
        la[i] = As + (wave * (BM / 4) + i * 16) * 32;
    }
    const short* gb0 = Bg + (long)(n0 + wave * 32 + lr) * K + le;
    const short* gb1 = gb0 + 16L * K;
    short* lb0 = Bs + (wave * 32) * 32;
    short* lb1 = lb0 + 16 * 32;

    f32x4 acc[MI][4];
    f32x4 zz = {0.f, 0.f, 0.f, 0.f};
#pragma unroll
    for (int i = 0; i < MI; ++i)
#pragma unroll
        for (int j = 0; j < 4; ++j) acc[i][j] = zz;

    int fr = lane & 15;
    int fk = (lane >> 4) * 8;
    int rm = wm * (BM / 2);

    for (int k0 = 0; k0 < K; k0 += 32) {
#pragma unroll
        for (int i = 0; i < NA; ++i) GLD16(ga[i] + k0, la[i]);
        GLD16(gb0 + k0, lb0);
        GLD16(gb1 + k0, lb1);
        __syncthreads();
        bf16x8 af[MI], bv[4];
#pragma unroll
        for (int mi = 0; mi < MI; ++mi)
            af[mi] = *(const bf16x8*)(As + (rm + mi * 16 + fr) * 32 + fk);
#pragma unroll
        for (int ni = 0; ni < 4; ++ni)
            bv[ni] = *(const bf16x8*)(Bs + (wn * 64 + ni * 16 + fr) * 32 + fk);
#pragma unroll
        for (int mi = 0; mi < MI; ++mi)
#pragma unroll
            for (int ni = 0; ni < 4; ++ni)
                acc[mi][ni] = __builtin_amdgcn_mfma_f32_16x16x32_bf16(
                    af[mi], bv[ni], acc[mi][ni], 0, 0, 0);
        __syncthreads();
    }

    int cc = lane & 15, cr = (lane >> 4) * 4;
    long cbase = (long)blockIdx.z * bsC;
#pragma unroll
    for (int mi = 0; mi < MI; ++mi) {
#pragma unroll
        for (int ni = 0; ni < 4; ++ni) {
            int row0 = m0 + rm + mi * 16 + cr;
            int col = n0 + wn * 64 + ni * 16 + cc;
            float bvl;
            long colterm;
            int md, rowstride;
            if (planeStride) {
                int plane = col >> 9;
                int c2 = col & 511;
                const float* bp = (plane == 0) ? b0 : ((plane == 1) ? b1 : b2);
                bvl = bp[c2];
                md = (modes >> (2 * plane)) & 3;
                colterm = (long)plane * planeStride + c2;
                rowstride = 512;
            } else {
                bvl = b0 ? b0[col] : 0.0f;
                md = modes & 3;
                colterm = col;
                rowstride = N;
            }
#pragma unroll
            for (int r = 0; r < 4; ++r) {
                float v = acc[mi][ni][r] + bvl;
                if (md == 1) v = 1.0f / (1.0f + expf(-v));
                else if (md == 2) v = 0.5f * v * (1.0f + erff(v * 0.70710678118654752f));
                long idx = cbase + (long)(row0 + r) * rowstride + colterm;
                if (resf) v += resf[idx];
                if (resb) v += ldf(resb, idx);
                if (Cf) Cf[idx] = v;
                else Cb[idx] = __float2bfloat16(v);
            }
        }
    }
}

// ------------- fused AFT GEMM + gating: Yt = sigQ * (ew@numT) / (ew@denT) ----------
// A = ew [T,T]; Bt = kv2t [1024,T] per batch z. Block: 128 A-rows x 64 c2 cols.
// Waves 0,1 (wn=0) compute num (Bt rows n0c..+64); waves 2,3 (wn=1) den (512+n0c..).
// Post-loop: den exchanged via LDS, wn=0 waves write Yt in place over sigQ.
__global__ __launch_bounds__(256, 2) void aft_gemm(
    const bf16* __restrict__ ew, const bf16* __restrict__ kv2t,
    bf16* __restrict__ qy) {
    __shared__ short S[128 * 32 * 2];
    short* As = S;
    short* Bs = S + 128 * 32;
    int tid = threadIdx.x;
    int lane = tid & 63, wave = tid >> 6;
    int wm = wave & 1, wn = wave >> 1, wb = wave & 1;
    int m0 = blockIdx.y * 128, n0c = blockIdx.x * 64, z = blockIdx.z;
    const short* Ag = (const short*)ew;
    const short* Bg = (const short*)kv2t + ((long)z << 21);

    int lr = lane >> 2;
    int le = (lane & 3) * 8;
    const short* ga0 = Ag + (long)(m0 + wave * 32 + lr) * T_ + le;
    const short* ga1 = ga0 + 16L * T_;
    short* la0 = As + (wave * 32) * 32;
    short* la1 = la0 + 16 * 32;
    // B: wave {0,1} -> num rows n0c+wb*32.., wave {2,3} -> den rows 512+n0c+wb*32..
    const short* gb0 = Bg + (long)(wn * 512 + n0c + wb * 32 + lr) * T_ + le;
    const short* gb1 = gb0 + 16L * T_;
    short* lb0 = Bs + (wave * 32) * 32;
    short* lb1 = lb0 + 16 * 32;

    f32x4 acc[4][4];
    f32x4 zz = {0.f, 0.f, 0.f, 0.f};
#pragma unroll
    for (int i = 0; i < 4; ++i)
#pragma unroll
        for (int j = 0; j < 4; ++j) acc[i][j] = zz;

    int fr = lane & 15;
    int fk = (lane >> 4) * 8;
    int rm = wm * 64;

    for (int k0 = 0; k0 < T_; k0 += 32) {
        GLD16(ga0 + k0, la0);
        GLD16(ga1 + k0, la1);
        GLD16(gb0 + k0, lb0);
        GLD16(gb1 + k0, lb1);
        __syncthreads();
        bf16x8 af[4], bv[4];
#pragma unroll
        for (int mi = 0; mi < 4; ++mi)
            af[mi] = *(const bf16x8*)(As + (rm + mi * 16 + fr) * 32 + fk);
#pragma unroll
        for (int ni = 0; ni < 4; ++ni)
            bv[ni] = *(const bf16x8*)(Bs + (wn * 64 + ni * 16 + fr) * 32 + fk);
#pragma unroll
        for (int mi = 0; mi < 4; ++mi)
#pragma unroll
            for (int ni = 0; ni < 4; ++ni)
                acc[mi][ni] = __builtin_amdgcn_mfma_f32_16x16x32_bf16(
                    af[mi], bv[ni], acc[mi][ni], 0, 0, 0);
        __syncthreads();
    }

    // exchange den via LDS (den_s[row 0..127][c2 0..63], bf16 in S = 16 KB)
    int cc = lane & 15, cr = (lane >> 4) * 4;
    short* den_s = S;
    if (wn == 1) {
#pragma unroll
        for (int mi = 0; mi < 4; ++mi)
#pragma unroll
            for (int ni = 0; ni < 4; ++ni) {
                int rowl = rm + mi * 16 + cr;
                int c2l = ni * 16 + cc;
#pragma unroll
                for (int r = 0; r < 4; ++r) {
                    bf16 d = __float2bfloat16(acc[mi][ni][r]);
                    den_s[(rowl + r) * 64 + c2l] = *(short*)&d;
                }
            }
    }
    __syncthreads();
    if (wn == 0) {
#pragma unroll
        for (int mi = 0; mi < 4; ++mi)
#pragma unroll
            for (int ni = 0; ni < 4; ++ni) {
                int rowl = rm + mi * 16 + cr;
                int c2l = ni * 16 + cc;
#pragma unroll
                for (int r = 0; r < 4; ++r) {
                    float num = acc[mi][ni][r];
                    float den = b2f((unsigned short)den_s[(rowl + r) * 64 + c2l]);
                    long idx = ((long)z * T_ + m0 + rowl + r) * D_ + n0c + c2l;
                    float q = ldf(qy, idx);
                    qy[idx] = __float2bfloat16(q * num / den);
                }
            }
    }
}

extern "C" void kernel_launch(void* const* d_in, const int* in_sizes, int n_in,
                              void* d_out, int out_size, void* d_ws, size_t ws_size,
                              hipStream_t stream) {
    const float* x    = (const float*)d_in[0];
    const float* ln1g = (const float*)d_in[1];
    const float* ln1b = (const float*)d_in[2];
    const float* Wk   = (const float*)d_in[3];
    const float* bk   = (const float*)d_in[4];
    const float* Wv   = (const float*)d_in[5];
    const float* bv   = (const float*)d_in[6];
    const float* Wq   = (const float*)d_in[7];
    const float* bq   = (const float*)d_in[8];
    const float* w    = (const float*)d_in[9];
    const float* Wo   = (const float*)d_in[10];
    const float* bo   = (const float*)d_in[11];
    const float* ln2g = (const float*)d_in[12];
    const float* ln2b = (const float*)d_in[13];
    const float* W1   = (const float*)d_in[14];
    const float* b1   = (const float*)d_in[15];
    const float* W2   = (const float*)d_in[16];
    const float* b2   = (const float*)d_in[17];
    float* out = (float*)d_out;

    const long S_BTD = (long)B_ * T_ * D_;      // 8,388,608
    const long S_TT  = (long)T_ * T_;           // 4,194,304
    const long S_B2D = (long)B_ * T_ * 2 * D_;  // 16,777,216
    const long S_DD  = (long)D_ * D_;           // 262,144

    // Workspace (bf16 elems) ~126 MB:
    bf16* h1     = (bf16*)d_ws;            // later h2
    bf16* outres = h1 + S_BTD;
    bf16* ew     = outres + S_BTD;
    bf16* KVQ    = ew + S_TT;              // K|V|Q planes (3*S_BTD); later hH low
    bf16* kv2t   = KVQ + 3 * S_BTD;        // S_B2D; later hH high part
    bf16* WkT    = kv2t + S_B2D;
    bf16* WvT    = WkT + S_DD;
    bf16* WqT    = WvT + S_DD;
    bf16* WoT    = WqT + S_DD;
    bf16* W1T    = WoT + S_DD;             // [H,D]
    bf16* W2T    = W1T + (long)D_ * H_;    // [D,H]
    bf16* Kb  = KVQ;
    bf16* Vb  = KVQ + S_BTD;
    bf16* Qb  = KVQ + 2 * S_BTD;           // sigQ, then Yt in place
    bf16* hH  = KVQ;                       // spans KVQ(48MB)+kv2t(16MB of 32MB)
    bf16* h2  = h1;

    const int M = B_ * T_;  // 16384

    // 1. batched weight transposes
    WT6 p;
    p.src[0] = Wk; p.src[1] = Wv; p.src[2] = Wq; p.src[3] = Wo; p.src[4] = W1; p.src[5] = W2;
    p.dst[0] = WkT; p.dst[1] = WvT; p.dst[2] = WqT; p.dst[3] = WoT; p.dst[4] = W1T; p.dst[5] = W2T;
    p.K[0] = p.K[1] = p.K[2] = p.K[3] = 512; p.K[4] = 512; p.K[5] = 2048;
    p.N[0] = p.N[1] = p.N[2] = p.N[3] = 512; p.N[4] = 2048; p.N[5] = 512;
    wtrans6_kernel<<<dim3(32, 32, 6), 256, 0, stream>>>(p);
    // 2. h1 = LN1(x)
    ln_kernel<float><<<M, 256, 0, stream>>>(x, ln1g, ln1b, h1);
    // 3. K|V|sigQ GEMM: N=1536 over [WkT;WvT;WqT], 3 planes -> Kb,Vb,Qb
    mfma_gemm<256><<<dim3(1536 / 128, M / 256, 1), 256, 0, stream>>>(
        h1, WkT, bk, bv, bq, Kb, nullptr, nullptr, nullptr,
        M, 1536, D_, (1 << 4), 0, 0, S_BTD);
    // 4. fused batch-max + kv2t
    maxkv2t_kernel<<<dim3(T_ / 64, D_ / 64, 1), 256, 0, stream>>>(Kb, Vb, kv2t);
    // 5. exp_w
    expw_kernel<<<T_, 256, 0, stream>>>(w, ew);
    // 6. fused AFT GEMM + gating: Yt in place over Qb
    aft_gemm<<<dim3(D_ / 64, T_ / 128, B_), 256, 0, stream>>>(ew, kv2t, Qb);
    // 7. out = Yt@Wo + bo + x
    mfma_gemm<128><<<dim3(D_ / 128, M / 128, 1), 256, 0, stream>>>(
        Qb, WoT, bo, nullptr, nullptr, outres, nullptr, nullptr, x,
        M, D_, D_, 0, 0, 0, 0);
    // 8. h2 = LN2(out)
    ln_kernel<bf16><<<M, 256, 0, stream>>>(outres, ln2g, ln2b, h2);
    // 9. hH = gelu(h2@W1 + b1)  (overwrites KVQ/kv2t span)
    mfma_gemm<256><<<dim3(H_ / 128, M / 256, 1), 256, 0, stream>>>(
        h2, W1T, b1, nullptr, nullptr, hH, nullptr, nullptr, nullptr,
        M, H_, D_, 2, 0, 0, 0);
    // 10. y = gelu(hH@W2 + b2) + out -> f32 d_out
    mfma_gemm<128><<<dim3(D_ / 128, M / 128, 1), 256, 0, stream>>>(
        hH, W2T, b2, nullptr, nullptr, nullptr, out, outres, nullptr,
        M, D_, H_, 2, 0, 0, 0);
}

// Round 8
// 609.517 us; speedup vs baseline: 1.1462x; 1.1462x over previous
//
#include <hip/hip_runtime.h>
#include <hip/hip_bf16.h>
#include <math.h>

typedef __hip_bfloat16 bf16;
typedef __bf16 bf16x8 __attribute__((ext_vector_type(8)));
typedef float f32x4 __attribute__((ext_vector_type(4)));

#define B_ 8
#define T_ 2048
#define D_ 512
#define H_ 2048

__device__ __forceinline__ float b2f(unsigned short u) {
    return __uint_as_float((unsigned)u << 16);
}
__device__ __forceinline__ float ldf(const float* p, long i) { return p[i]; }
__device__ __forceinline__ float ldf(const bf16* p, long i) {
    return b2f(((const unsigned short*)p)[i]);
}
// tanh-form gelu: v*sigmoid(1.59577(v+0.044715 v^3)); |err| < 1e-3 abs
__device__ __forceinline__ float gelu_f(float v) {
    float a = 1.5957691216057308f * (v + 0.044715f * v * v * v);
    return v / (1.0f + __expf(-a));
}

#define GLD16(g, l)                                                          \
    __builtin_amdgcn_global_load_lds(                                        \
        (const __attribute__((address_space(1))) void*)(g),                  \
        (__attribute__((address_space(3))) void*)(l), 16, 0, 0)

// ---------------- LayerNorm over D=512, one block (256 thr) per row ----------------
template <typename Tin>
__global__ __launch_bounds__(256) void ln_kernel(const Tin* __restrict__ x,
                                                 const float* __restrict__ g,
                                                 const float* __restrict__ bb,
                                                 bf16* __restrict__ y) {
    long base = (long)blockIdx.x * D_;
    int tid = threadIdx.x;
    float v0 = ldf(x, base + tid);
    float v1 = ldf(x, base + tid + 256);
    float s = v0 + v1;
#pragma unroll
    for (int off = 32; off > 0; off >>= 1) s += __shfl_down(s, off);
    __shared__ float red[4];
    int lane = tid & 63, wid = tid >> 6;
    if (lane == 0) red[wid] = s;
    __syncthreads();
    float mean = (red[0] + red[1] + red[2] + red[3]) * (1.0f / 512.0f);
    __syncthreads();
    float d0 = v0 - mean, d1 = v1 - mean;
    float vs = d0 * d0 + d1 * d1;
#pragma unroll
    for (int off = 32; off > 0; off >>= 1) vs += __shfl_down(vs, off);
    if (lane == 0) red[wid] = vs;
    __syncthreads();
    float var = (red[0] + red[1] + red[2] + red[3]) * (1.0f / 512.0f);
    float rstd = rsqrtf(var + 1e-5f);
    y[base + tid]       = __float2bfloat16(d0 * rstd * g[tid]       + bb[tid]);
    y[base + tid + 256] = __float2bfloat16(d1 * rstd * g[tid + 256] + bb[tid + 256]);
}

// ---------------- exp(w - rowmax(w)) : one block per row of [T,T] ----------------
__global__ __launch_bounds__(256) void expw_kernel(const float* __restrict__ w,
                                                   bf16* __restrict__ ew) {
    long base = (long)blockIdx.x * T_;
    int tid = threadIdx.x;
    float v[8];
    float mx = -3.4e38f;
#pragma unroll
    for (int i = 0; i < 8; ++i) {
        v[i] = w[base + tid + i * 256];
        mx = fmaxf(mx, v[i]);
    }
#pragma unroll
    for (int off = 32; off > 0; off >>= 1) mx = fmaxf(mx, __shfl_down(mx, off));
    __shared__ float red[4];
    if ((tid & 63) == 0) red[tid >> 6] = mx;
    __syncthreads();
    float rmax = fmaxf(fmaxf(red[0], red[1]), fmaxf(red[2], red[3]));
#pragma unroll
    for (int i = 0; i < 8; ++i)
        ew[base + tid + i * 256] = __float2bfloat16(expf(v[i] - rmax));
}

// ---------------- max over batch dim of K [B,T,D] -> [T*D] (f32) ----------------
__global__ __launch_bounds__(256) void maxk_kernel(const bf16* __restrict__ K,
                                                   float* __restrict__ mk) {
    long i = (long)blockIdx.x * 256 + threadIdx.x;
    float m = ldf(K, i);
#pragma unroll
    for (int b = 1; b < B_; ++b) m = fmaxf(m, ldf(K, (long)b * (T_ * D_) + i));
    mk[i] = m;
}

// ------- build kv2T[b][n][t], n<512: expK*V (d=n); n>=512: expK (d=n-512) -------
__global__ __launch_bounds__(256) void kv2t_kernel(const bf16* __restrict__ K_,
                                                   const bf16* __restrict__ V_,
                                                   const float* __restrict__ mk,
                                                   bf16* __restrict__ kv2t) {
    __shared__ float sev[64][65];
    __shared__ float se[64][65];
    int tx = threadIdx.x & 63, ty = threadIdx.x >> 6;
    int t0 = blockIdx.x * 64, d0 = blockIdx.y * 64, b = blockIdx.z;
    long ibase = (long)b << 20;
#pragma unroll
    for (int r = 0; r < 16; ++r) {
        int tl = r * 4 + ty;
        long mi = (long)(t0 + tl) * D_ + d0 + tx;
        float e = expf(ldf(K_, ibase + mi) - mk[mi]);
        sev[tl][tx] = e * ldf(V_, ibase + mi);
        se[tl][tx] = e;
    }
    __syncthreads();
    long obase = (long)b << 21;
#pragma unroll
    for (int r = 0; r < 16; ++r) {
        int dl = r * 4 + ty;
        kv2t[obase + (long)(d0 + dl) * T_ + t0 + tx]        = __float2bfloat16(sev[tx][dl]);
        kv2t[obase + (long)(512 + d0 + dl) * T_ + t0 + tx]  = __float2bfloat16(se[tx][dl]);
    }
}

// ---------------- Yt = sigQ * num/den, in place on sigQ ----------------
__global__ __launch_bounds__(256) void yt_kernel(const bf16* __restrict__ nd,
                                                 bf16* __restrict__ q) {
    long i = (long)blockIdx.x * 256 + threadIdx.x;
    long td = i & (long)(T_ * D_ - 1);
    long b = i >> 20;
    long t = td >> 9;
    long d = td & (D_ - 1);
    long base = (b << 21) + (t << 10);
    float num = ldf(nd, base + d), den = ldf(nd, base + D_ + d);
    q[i] = __float2bfloat16(ldf(q, i) * num / den);
}

// ---------------- batched weight transpose + f32->bf16: W[K,N] -> WT[N,K] ----------
struct WT6 {
    const float* src[6];
    bf16* dst[6];
    int K[6], N[6];
};
__global__ __launch_bounds__(256) void wtrans6_kernel(WT6 p) {
    int z = blockIdx.z;
    int K = p.K[z], N = p.N[z];
    int n0 = blockIdx.x * 64, k0 = blockIdx.y * 64;
    if (n0 >= N || k0 >= K) return;
    const float* W = p.src[z];
    bf16* WT = p.dst[z];
    __shared__ float s[64][65];
    int tx = threadIdx.x & 63, ty = threadIdx.x >> 6;
#pragma unroll
    for (int r = 0; r < 16; ++r) {
        int kl = r * 4 + ty;
        s[kl][tx] = W[(long)(k0 + kl) * N + n0 + tx];
    }
    __syncthreads();
#pragma unroll
    for (int r = 0; r < 16; ++r) {
        int nl = r * 4 + ty;
        WT[(long)(n0 + nl) * K + k0 + tx] = __float2bfloat16(s[tx][nl]);
    }
}

// ---------------- MFMA GEMM: C = epi(A@Bt^T + bias) [+res] ------------------------
// BM x 128 macro-tile, 4 waves. planeStride!=0: N split into 512-col planes;
// per-plane bias b0/b1/b2 and mode=(modes>>(2*plane))&3. mode 0=none 1=sigmoid 2=gelu.
template <int BM>
__global__ __launch_bounds__(256, 2) void mfma_gemm(
    const bf16* __restrict__ A, const bf16* __restrict__ Bt,
    const float* __restrict__ b0, const float* __restrict__ b1,
    const float* __restrict__ b2,
    bf16* __restrict__ Cb, float* __restrict__ Cf,
    const bf16* __restrict__ resb, const float* __restrict__ resf,
    int M, int N, int K, int modes, long bsB, long bsC, long planeStride) {
    constexpr int MI = BM / 32;
    constexpr int NA = BM / 64;
    __shared__ short As[BM * 32];
    __shared__ short Bs[128 * 32];
    int tid = threadIdx.x;
    int lane = tid & 63, wave = tid >> 6;
    int wm = wave & 1, wn = wave >> 1;
    int m0 = blockIdx.y * BM, n0 = blockIdx.x * 128;
    const short* Ag = (const short*)A;
    const short* Bg = (const short*)Bt + (long)blockIdx.z * bsB;

    int lr = lane >> 2;
    int le = (lane & 3) * 8;
    const short* ga[NA];
    short* la[NA];
#pragma unroll
    for (int i = 0; i < NA; ++i) {
        ga[i] = Ag + (long)(m0 + wave * (BM / 4) + i * 16 + lr) * K + le;
        la[i] = As + (wave * (BM / 4) + i * 16) * 32;
    }
    const short* gb0 = Bg + (long)(n0 + wave * 32 + lr) * K + le;
    const short* gb1 = gb0 + 16L * K;
    short* lb0 = Bs + (wave * 32) * 32;
    short* lb1 = lb0 + 16 * 32;

    f32x4 acc[MI][4];
    f32x4 zz = {0.f, 0.f, 0.f, 0.f};
#pragma unroll
    for (int i = 0; i < MI; ++i)
#pragma unroll
        for (int j = 0; j < 4; ++j) acc[i][j] = zz;

    int fr = lane & 15;
    int fk = (lane >> 4) * 8;
    int rm = wm * (BM / 2);

    for (int k0 = 0; k0 < K; k0 += 32) {
#pragma unroll
        for (int i = 0; i < NA; ++i) GLD16(ga[i] + k0, la[i]);
        GLD16(gb0 + k0, lb0);
        GLD16(gb1 + k0, lb1);
        __syncthreads();
        bf16x8 af[MI], bv[4];
#pragma unroll
        for (int mi = 0; mi < MI; ++mi)
            af[mi] = *(const bf16x8*)(As + (rm + mi * 16 + fr) * 32 + fk);
#pragma unroll
        for (int ni = 0; ni < 4; ++ni)
            bv[ni] = *(const bf16x8*)(Bs + (wn * 64 + ni * 16 + fr) * 32 + fk);
#pragma unroll
        for (int mi = 0; mi < MI; ++mi)
#pragma unroll
            for (int ni = 0; ni < 4; ++ni)
                acc[mi][ni] = __builtin_amdgcn_mfma_f32_16x16x32_bf16(
                    af[mi], bv[ni], acc[mi][ni], 0, 0, 0);
        __syncthreads();
    }

    int cc = lane & 15, cr = (lane >> 4) * 4;
    long cbase = (long)blockIdx.z * bsC;
#pragma unroll
    for (int mi = 0; mi < MI; ++mi) {
#pragma unroll
        for (int ni = 0; ni < 4; ++ni) {
            int row0 = m0 + rm + mi * 16 + cr;
            int col = n0 + wn * 64 + ni * 16 + cc;
            float bvl;
            long colterm;
            int md, rowstride;
            if (planeStride) {
                int plane = col >> 9;
                int c2 = col & 511;
                const float* bp = (plane == 0) ? b0 : ((plane == 1) ? b1 : b2);
                bvl = bp[c2];
                md = (modes >> (2 * plane)) & 3;
                colterm = (long)plane * planeStride + c2;
                rowstride = 512;
            } else {
                bvl = b0 ? b0[col] : 0.0f;
                md = modes & 3;
                colterm = col;
                rowstride = N;
            }
#pragma unroll
            for (int r = 0; r < 4; ++r) {
                float v = acc[mi][ni][r] + bvl;
                if (md == 1) v = 1.0f / (1.0f + __expf(-v));
                else if (md == 2) v = gelu_f(v);
                long idx = cbase + (long)(row0 + r) * rowstride + colterm;
                if (resf) v += resf[idx];
                if (resb) v += ldf(resb, idx);
                if (Cf) Cf[idx] = v;
                else Cb[idx] = __float2bfloat16(v);
            }
        }
    }
}

extern "C" void kernel_launch(void* const* d_in, const int* in_sizes, int n_in,
                              void* d_out, int out_size, void* d_ws, size_t ws_size,
                              hipStream_t stream) {
    const float* x    = (const float*)d_in[0];
    const float* ln1g = (const float*)d_in[1];
    const float* ln1b = (const float*)d_in[2];
    const float* Wk   = (const float*)d_in[3];
    const float* bk   = (const float*)d_in[4];
    const float* Wv   = (const float*)d_in[5];
    const float* bv   = (const float*)d_in[6];
    const float* Wq   = (const float*)d_in[7];
    const float* bq   = (const float*)d_in[8];
    const float* w    = (const float*)d_in[9];
    const float* Wo   = (const float*)d_in[10];
    const float* bo   = (const float*)d_in[11];
    const float* ln2g = (const float*)d_in[12];
    const float* ln2b = (const float*)d_in[13];
    const float* W1   = (const float*)d_in[14];
    const float* b1   = (const float*)d_in[15];
    const float* W2   = (const float*)d_in[16];
    const float* b2   = (const float*)d_in[17];
    float* out = (float*)d_out;

    const long S_BTD = (long)B_ * T_ * D_;      // 8,388,608
    const long S_TD  = (long)T_ * D_;           // 1,048,576
    const long S_TT  = (long)T_ * T_;           // 4,194,304
    const long S_B2D = (long)B_ * T_ * 2 * D_;  // 16,777,216
    const long S_DD  = (long)D_ * D_;           // 262,144

    // Workspace (bf16 elems unless noted) ~136 MB:
    bf16* h1     = (bf16*)d_ws;            // later h2
    bf16* outres = h1 + S_BTD;
    bf16* ew     = outres + S_BTD;
    bf16* KVQ    = ew + S_TT;              // K|V|Q planes (3*S_BTD)
    bf16* kv2t   = KVQ + 3 * S_BTD;        // S_B2D
    float* mk    = (float*)(kv2t + S_B2D); // S_TD f32
    bf16* WkT    = (bf16*)(mk + S_TD);
    bf16* WvT    = WkT + S_DD;
    bf16* WqT    = WvT + S_DD;
    bf16* WoT    = WqT + S_DD;
    bf16* W1T    = WoT + S_DD;             // [H,D]
    bf16* W2T    = W1T + (long)D_ * H_;    // [D,H]
    bf16* Kb  = KVQ;
    bf16* Vb  = KVQ + S_BTD;
    bf16* Qb  = KVQ + 2 * S_BTD;           // sigQ, then Yt in place
    bf16* nd  = KVQ;                       // overwrites K|V planes after kv2t
    bf16* hH  = KVQ;                       // spans KVQ(24M)+kv2t(16M) >= 33.6M elems
    bf16* h2  = h1;

    const int M = B_ * T_;  // 16384

    // 1. batched weight transposes
    WT6 p;
    p.src[0] = Wk; p.src[1] = Wv; p.src[2] = Wq; p.src[3] = Wo; p.src[4] = W1; p.src[5] = W2;
    p.dst[0] = WkT; p.dst[1] = WvT; p.dst[2] = WqT; p.dst[3] = WoT; p.dst[4] = W1T; p.dst[5] = W2T;
    p.K[0] = p.K[1] = p.K[2] = p.K[3] = 512; p.K[4] = 512; p.K[5] = 2048;
    p.N[0] = p.N[1] = p.N[2] = p.N[3] = 512; p.N[4] = 2048; p.N[5] = 512;
    wtrans6_kernel<<<dim3(32, 32, 6), 256, 0, stream>>>(p);
    // 2. h1 = LN1(x)
    ln_kernel<float><<<M, 256, 0, stream>>>(x, ln1g, ln1b, h1);
    // 3. K|V|sigQ GEMM: N=1536 over [WkT;WvT;WqT], 3 planes -> Kb,Vb,Qb
    mfma_gemm<256><<<dim3(1536 / 128, M / 256, 1), 256, 0, stream>>>(
        h1, WkT, bk, bv, bq, Kb, nullptr, nullptr, nullptr,
        M, 1536, D_, (1 << 4), 0, 0, S_BTD);
    // 4. mk = max_b K; 5. kv2t = [expK*V | expK]^T per batch
    maxk_kernel<<<S_TD / 256, 256, 0, stream>>>(Kb, mk);
    kv2t_kernel<<<dim3(T_ / 64, D_ / 64, B_), 256, 0, stream>>>(Kb, Vb, mk, kv2t);
    // 6. exp_w
    expw_kernel<<<T_, 256, 0, stream>>>(w, ew);
    // 7. nd[b] = ew @ kv2t[b]^T  (M=2048, N=1024, K=2048) — overwrites K|V planes
    mfma_gemm<256><<<dim3(1024 / 128, T_ / 256, B_), 256, 0, stream>>>(
        ew, kv2t, nullptr, nullptr, nullptr, nd, nullptr, nullptr, nullptr,
        T_, 1024, T_, 0, (long)1024 * T_, (long)T_ * 1024, 0);
    // 8. Yt = sigQ * num/den (in place on Qb)
    yt_kernel<<<S_BTD / 256, 256, 0, stream>>>(nd, Qb);
    // 9. out = Yt@Wo + bo + x
    mfma_gemm<128><<<dim3(D_ / 128, M / 128, 1), 256, 0, stream>>>(
        Qb, WoT, bo, nullptr, nullptr, outres, nullptr, nullptr, x,
        M, D_, D_, 0, 0, 0, 0);
    // 10. h2 = LN2(out)
    ln_kernel<bf16><<<M, 256, 0, stream>>>(outres, ln2g, ln2b, h2);
    // 11. hH = gelu(h2@W1 + b1)  (overwrites KVQ/kv2t span)
    mfma_gemm<256><<<dim3(H_ / 128, M / 256, 1), 256, 0, stream>>>(
        h2, W1T, b1, nullptr, nullptr, hH, nullptr, nullptr, nullptr,
        M, H_, D_, 2, 0, 0, 0);
    // 12. y = gelu(hH@W2 + b2) + out -> f32 d_out
    mfma_gemm<128><<<dim3(D_ / 128, M / 128, 1), 256, 0, stream>>>(
        hH, W2T, b2, nullptr, nullptr, nullptr, out, outres, nullptr,
        M, D_, H_, 2, 0, 0, 0);
}